// Round 6
// baseline (555.866 us; speedup 1.0000x reference)
//
#include <hip/hip_runtime.h>
#include <math.h>

// Problem constants
#define BATCH 32
#define TLEN  4096
#define DDIM  512
#define BM    32      // rows per block (32 KB LDS -> 2 blocks/CU co-resident)
#define BLOCK 512     // 8 waves; wave w owns output cols [64w, 64w+64)
// r12: deep software pipeline. r11 proved doubling TLP leaves dur flat with
// per-block latency scaling ~2x with residency -> k-loop steady state is
// pinned by exposed L2 latency on W loads (1-deep prefetch = ~100cyc slack
// vs ~300-500cyc latency; 32 iters x ~330cyc ~= the measured 84k cyc/block).
// r11's VGPR=64 under a 128 cap shows the compiler never deepened the
// pipeline itself. Now: full unroll of both 16-iter k-loops with an explicit
// 3-stage W pipeline (2 iters slack) + 2-stage LDS pipeline for GEMM1.
// All pipeline indices compile-time (i%3, i&1) -> registers, no scratch.
// Peak pressure ~119 < 128 cap -> still 2 blocks/CU, 4 waves/SIMD.

typedef __attribute__((ext_vector_type(8)))  short bf16x8;   // MFMA A/B frag
typedef __attribute__((ext_vector_type(16))) float f32x16;   // MFMA C/D frag (32x32)
typedef __attribute__((ext_vector_type(4)))  short s16x4;    // 8B LDS store

__device__ __forceinline__ short f32_to_bf16_rne(float f) {
    union { float f; unsigned int u; } v; v.f = f;
    unsigned int r = (v.u + 0x7FFFu + ((v.u >> 16) & 1u)) >> 16;
    return (short)r;
}
__device__ __forceinline__ float bf16_to_f32(unsigned int s) {
    union { unsigned int u; float f; } v;
    v.u = (s & 0xFFFFu) << 16;
    return v.f;
}
__device__ __forceinline__ float fast_tanh(float x) {
    x = fminf(fmaxf(x, -15.f), 15.f);
    float t = __expf(2.0f * x);
    return (t - 1.0f) / (t + 1.0f);
}

// XOR swizzle on 16B (8-short) granules.
__device__ __forceinline__ int lds_idx(int r, int c) {
    int g = (c >> 3) ^ (r & 31);
    return r * DDIM + (g << 3) + (c & 7);
}

// --- kernel 1: W fp32 -> bf16 packed into MFMA-fragment order; zero l/g ------
// Element (e, d): E=e>>5, r=e&31, C=d>>4, half=(d>>3)&1, j=d&7
//   packed[ ((E*32 + C)*64 + half*32 + r)*8 + j ]
// Kernel-side (lane l): tile (E,C) base + l*8 supplies
//   W[E*32 + (l&31)][C*16 + 8*(l>>5) + j]  == MFMA fragment element.
__global__ void prep_kernel(const float* __restrict__ W1, const float* __restrict__ W2,
                            short* __restrict__ W1pk, short* __restrict__ W2pk,
                            float* __restrict__ lbuf, float* __restrict__ gbuf) {
    int i = blockIdx.x * blockDim.x + threadIdx.x;   // 0 .. 32767
    int e  = i >> 6;                 // source row
    int d0 = (i & 63) << 3;          // source col of this 8-run
    int E = e >> 5, r = e & 31, C = d0 >> 4, half = (d0 >> 3) & 1;
    size_t src = (size_t)e * DDIM + d0;
    size_t dst = ((size_t)(E * 32 + C) * 64 + half * 32 + r) * 8;
    bf16x8 p1, p2;
    #pragma unroll
    for (int j = 0; j < 8; ++j) {
        p1[j] = f32_to_bf16_rne(W1[src + j]);
        p2[j] = f32_to_bf16_rne(W2[src + j]);
    }
    *(bf16x8*)&W1pk[dst] = p1;
    *(bf16x8*)&W2pk[dst] = p2;
    if (i < BATCH * DDIM) { lbuf[i] = 0.f; gbuf[i] = 0.f; }
}

// --- kernel 2: fused u=tanh(hW1^T+b1); s=uW2^T; accumulate l,g ---------------
__global__ __launch_bounds__(BLOCK, 4)   // cap 128 VGPR -> 2 blocks/CU
void main_kernel(const float* __restrict__ h,
                 const short* __restrict__ W1pk,
                 const float* __restrict__ b1,
                 const short* __restrict__ W2pk,
                 float* __restrict__ lbuf, float* __restrict__ gbuf) {
    __shared__ __align__(16) short sh[BM * DDIM];   // 32 KB: h tile, then u tile

    const int tid  = threadIdx.x;
    const int row0 = blockIdx.x * BM;
    const int b    = row0 / TLEN;       // BM divides TLEN: no batch straddle

    // ---- stage: global fp32 h -> LDS bf16 (coalesced float4 loads) ----
    {
        const float4* hp = (const float4*)(h + (size_t)row0 * DDIM);
        #pragma unroll
        for (int i = 0; i < (BM * DDIM / 4) / BLOCK; ++i) {   // 8 iters
            int idx  = tid + i * BLOCK;          // float4 index
            float4 v = hp[idx];
            int flat = idx * 4;
            int r = flat >> 9;                   // /512
            int c = flat & (DDIM - 1);
            s16x4 p;
            p.x = f32_to_bf16_rne(v.x); p.y = f32_to_bf16_rne(v.y);
            p.z = f32_to_bf16_rne(v.z); p.w = f32_to_bf16_rne(v.w);
            *(s16x4*)&sh[lds_idx(r, c)] = p;
        }
    }
    __syncthreads();

    const int wave = tid >> 6;
    const int lane = tid & 63;
    const int l32  = lane & 31;
    const int h5   = lane >> 5;       // 0/1
    const int e0   = wave * 64;       // this wave's 64-col slice (both GEMMs)

    // ========== GEMM1 (swapped): C[e][t] = sum_d W1[e][d] * h[t][d] ==========
    // A-frag = W1 packed (coalesced: lane*16B), B-frag = h^T from LDS.
    f32x16 acc[2];                    // [eb]
    #pragma unroll
    for (int i = 0; i < 2; ++i)
        #pragma unroll
        for (int r = 0; r < 16; ++r) acc[i][r] = 0.f;

    const short* W1p = W1pk + (size_t)(e0 >> 5) * (32 * 512) + lane * 8;

    // W pipeline: 3 stages (2 iters of slack ~300-500cyc); chunk(i,ks) = 2i+ks
    bf16x8 wp[3][2][2];               // [stage][eb][ks]
    #pragma unroll
    for (int s = 0; s < 2; ++s)
        #pragma unroll
        for (int eb = 0; eb < 2; ++eb)
            #pragma unroll
            for (int ks = 0; ks < 2; ++ks)
                wp[s][eb][ks] = *(const bf16x8*)(W1p + (eb * 32 + 2 * s + ks) * 512);
    // LDS pipeline: 2 stages
    bf16x8 hp[2][2];                  // [buf][ks]
    #pragma unroll
    for (int ks = 0; ks < 2; ++ks)
        hp[0][ks] = *(const bf16x8*)&sh[lds_idx(l32, ks * 16 + 8 * h5)];

    #pragma unroll
    for (int i = 0; i < 16; ++i) {
        const int k0 = i * 32;
        if (i < 14) {                 // prefetch W two iters ahead
            #pragma unroll
            for (int eb = 0; eb < 2; ++eb)
                #pragma unroll
                for (int ks = 0; ks < 2; ++ks)
                    wp[(i + 2) % 3][eb][ks] =
                        *(const bf16x8*)(W1p + (eb * 32 + 2 * (i + 2) + ks) * 512);
        }
        if (i < 15) {                 // prefetch h frags one iter ahead
            #pragma unroll
            for (int ks = 0; ks < 2; ++ks)
                hp[(i + 1) & 1][ks] =
                    *(const bf16x8*)&sh[lds_idx(l32, k0 + 32 + ks * 16 + 8 * h5)];
        }
        #pragma unroll
        for (int eb = 0; eb < 2; ++eb)
            #pragma unroll
            for (int ks = 0; ks < 2; ++ks)
                acc[eb] = __builtin_amdgcn_mfma_f32_32x32x16_bf16(
                    wp[i % 3][eb][ks], hp[i & 1][ks], acc[eb], 0, 0, 0);
    }

    // issue GEMM2's first W2 pipeline stages: latency hides under tanh+bars
    const short* W2p = W2pk + (size_t)(e0 >> 5) * (32 * 512) + lane * 8;
    bf16x8 wp2[3][2][2];              // [stage][cb][ks]
    #pragma unroll
    for (int s = 0; s < 2; ++s)
        #pragma unroll
        for (int cb = 0; cb < 2; ++cb)
            #pragma unroll
            for (int ks = 0; ks < 2; ++ks)
                wp2[s][cb][ks] = *(const bf16x8*)(W2p + (cb * 32 + 2 * s + ks) * 512);

    // bias + tanh. C/D map: col(t)=lane&31, row(e)=(r&3)+8*(r>>2)+4*h5 (+32*eb)
    #pragma unroll
    for (int eb = 0; eb < 2; ++eb) {
        float4 bv[4];
        #pragma unroll
        for (int q = 0; q < 4; ++q)
            bv[q] = *(const float4*)&b1[e0 + 32 * eb + 4 * h5 + 8 * q];
        #pragma unroll
        for (int r = 0; r < 16; ++r)
            acc[eb][r] = fast_tanh(acc[eb][r] + bv[r >> 2][r & 3]);
    }

    // grab this thread's epilogue h values from LDS before u overwrites it.
    // epilogue needs h[tt][e2], tt = 4*h5 + (r&3) + 8*(r>>2), r = 0..15,
    // for e2 = e0 + 32*cb + l32. Pack pairs (r=2q, 2q+1) -> rows tt0, tt0+1.
    unsigned int hpk[2][8];
    #pragma unroll
    for (int cb = 0; cb < 2; ++cb) {
        int e2 = e0 + 32 * cb + l32;
        #pragma unroll
        for (int q = 0; q < 8; ++q) {
            int tt0 = 4 * h5 + ((2 * q) & 3) + 8 * (q >> 1);
            unsigned int lo = (unsigned short)sh[lds_idx(tt0, e2)];
            unsigned int hi = (unsigned short)sh[lds_idx(tt0 + 1, e2)];
            hpk[cb][q] = lo | (hi << 16);
        }
    }

    __syncthreads();   // all waves done reading h tile; safe to overwrite with u

    // write u^T frags as u[t][e]: lane owns fixed t=l32, 4-consec-e runs -> b64
    #pragma unroll
    for (int eb = 0; eb < 2; ++eb) {
        #pragma unroll
        for (int q = 0; q < 4; ++q) {
            int e = e0 + 32 * eb + 4 * h5 + 8 * q;
            s16x4 p;
            p.x = f32_to_bf16_rne(acc[eb][4 * q + 0]);
            p.y = f32_to_bf16_rne(acc[eb][4 * q + 1]);
            p.z = f32_to_bf16_rne(acc[eb][4 * q + 2]);
            p.w = f32_to_bf16_rne(acc[eb][4 * q + 3]);
            *(s16x4*)&sh[lds_idx(l32, e)] = p;
        }
    }
    __syncthreads();

    // ========== GEMM2 (normal): s[t][e2] = sum_e u[t][e] * W2[e2][e] =========
    f32x16 acc2[2];                   // [cb]
    #pragma unroll
    for (int i = 0; i < 2; ++i)
        #pragma unroll
        for (int r = 0; r < 16; ++r) acc2[i][r] = 0.f;

    #pragma unroll
    for (int i = 0; i < 16; ++i) {
        const int k0 = i * 32;
        if (i < 14) {                 // prefetch W2 two iters ahead
            #pragma unroll
            for (int cb = 0; cb < 2; ++cb)
                #pragma unroll
                for (int ks = 0; ks < 2; ++ks)
                    wp2[(i + 2) % 3][cb][ks] =
                        *(const bf16x8*)(W2p + (cb * 32 + 2 * (i + 2) + ks) * 512);
        }
        bf16x8 uf[2];                 // [ksub] (LDS, single-buffer: saves regs)
        #pragma unroll
        for (int ks = 0; ks < 2; ++ks)
            uf[ks] = *(const bf16x8*)&sh[lds_idx(l32, k0 + ks * 16 + 8 * h5)];
        #pragma unroll
        for (int cb = 0; cb < 2; ++cb)
            #pragma unroll
            for (int ks = 0; ks < 2; ++ks)
                acc2[cb] = __builtin_amdgcn_mfma_f32_32x32x16_bf16(
                    uf[ks], wp2[i % 3][cb][ks], acc2[cb], 0, 0, 0);
    }

    // epilogue: e = exp(s); l += e; g += e*h (h from packed LDS-grabbed regs).
    // lane holds 16 of 32 t's; partner (lane^32) holds the other 16.
    #pragma unroll
    for (int cb = 0; cb < 2; ++cb) {
        const int e2 = e0 + 32 * cb + l32;
        float lsum = 0.f, gsum = 0.f;
        #pragma unroll
        for (int r = 0; r < 16; ++r) {
            float hv = bf16_to_f32(hpk[cb][r >> 1] >> (16 * (r & 1)));
            float ev = __expf(acc2[cb][r]);       // |s| small: no max-sub
            lsum += ev;
            gsum += ev * hv;
        }
        lsum += __shfl_xor(lsum, 32);
        gsum += __shfl_xor(gsum, 32);
        if (h5 == 0) {
            atomicAdd(&lbuf[b * DDIM + e2], lsum);
            atomicAdd(&gbuf[b * DDIM + e2], gsum);
        }
    }
}

// --- kernel 3: out[d] = sum_b g[b,d] / l[b,d] --------------------------------
__global__ void finish_kernel(const float* __restrict__ lbuf,
                              const float* __restrict__ gbuf,
                              float* __restrict__ out) {
    int d = blockIdx.x * blockDim.x + threadIdx.x;   // 0..511
    float s = 0.f;
    #pragma unroll
    for (int b = 0; b < BATCH; ++b)
        s += gbuf[b * DDIM + d] / lbuf[b * DDIM + d];
    out[d] = s;
}

extern "C" void kernel_launch(void* const* d_in, const int* in_sizes, int n_in,
                              void* d_out, int out_size, void* d_ws, size_t ws_size,
                              hipStream_t stream) {
    const float* h  = (const float*)d_in[0];
    const float* W1 = (const float*)d_in[1];
    const float* b1 = (const float*)d_in[2];
    const float* W2 = (const float*)d_in[3];
    float* out = (float*)d_out;

    char* ws = (char*)d_ws;
    short* W1pk = (short*)ws;                             // 512 KB (packed)
    short* W2pk = (short*)(ws + 512 * 1024);              // 512 KB (packed)
    float* lbuf = (float*)(ws + 1024 * 1024);             // 64 KB
    float* gbuf = (float*)(ws + 1024 * 1024 + 64 * 1024); // 64 KB

    prep_kernel<<<128, 256, 0, stream>>>(W1, W2, W1pk, W2pk, lbuf, gbuf);
    main_kernel<<<(BATCH * TLEN) / BM, BLOCK, 0, stream>>>(h, W1pk, b1, W2pk, lbuf, gbuf);
    finish_kernel<<<2, 256, 0, stream>>>(lbuf, gbuf, out);
}